// Round 5
// baseline (67.222 us; speedup 1.0000x reference)
//
#include <hip/hip_runtime.h>

#define WINDOW 128
#define H 32
#define O2 256
#define LFRAMES 65536
#define WU 32
#define FO_BLK 128     // output frames per block
#define FMID 160       // mid-chain frames per block (FO + 32 warmup)
#define FSS 192        // staged x frames per block (FO + 64 warmup)

using bf16x8 = __attribute__((ext_vector_type(8))) short;
using f32x4  = __attribute__((ext_vector_type(4))) float;
using u16x4  = __attribute__((ext_vector_type(4))) unsigned short;

__device__ __forceinline__ unsigned bf16r(float v) {   // RTNE float->bf16 bits
    unsigned u = __builtin_bit_cast(unsigned, v);
    return (u + 0x7FFFu + ((u >> 16) & 1u)) >> 16;
}
__device__ __forceinline__ float bf2f(unsigned s) {
    return __builtin_bit_cast(float, s << 16);
}
__device__ __forceinline__ float selu_f(float x) {
    const float scale = 1.0507009873554805f;
    const float alpha = 1.6732632423543772f;
    return scale * (x > 0.0f ? x : alpha * (expf(x) - 1.0f));
}
__device__ __forceinline__ bf16x8 cvt8(float4 a, float4 b) {
    bf16x8 r;
    r[0] = (short)bf16r(a.x); r[1] = (short)bf16r(a.y);
    r[2] = (short)bf16r(a.z); r[3] = (short)bf16r(a.w);
    r[4] = (short)bf16r(b.x); r[5] = (short)bf16r(b.y);
    r[6] = (short)bf16r(b.z); r[7] = (short)bf16r(b.w);
    return r;
}

// ---------------- LDS byte offsets (total 81280 -> 2 blocks/CU) -------------
#define OFF_C1HI   0        // [32][64+4] bf16, pitch 136B   (4352)
#define OFF_C1LO   4352
#define OFF_MWHI   8704     // [32][32+4] bf16, pitch 72B    (2304)
#define OFF_MWLO   11008
#define OFF_B2HI   13312    // [64][32+4] bf16, pitch 72B    (4608)
#define OFF_B2LO   17920
#define OFF_BIAS   22528    // [32] f32                      (128)
#define OFF_R1     22656    // u1 [192]p132 (25344) | y1s [160]p72 | h2 [128]p136
#define OFF_R2     48000    // d1x [160]p72 (11520) | y2l [160]p72
#define OFF_R3     59520    // h1 [160]p136 (21760) | u2s [160]p132
#define S_LDS      81280

// ---------------------------------------------------------------------------
// prep: W1 (96x128) and Wcat (256x96) as bf16 hi/lo in ws.
// W1 rows 0..63 interleaved (2c=b1r[c], 2c+1=b1i[c]), 64..95 = d1.
// Wcat k<64: even->c2r, odd->-c2i; k>=64: d2.
// ---------------------------------------------------------------------------
__global__ void prep_weights(const float* __restrict__ b1r, const float* __restrict__ b1i,
                             const float* __restrict__ d1,
                             const float* __restrict__ c2r, const float* __restrict__ c2i,
                             const float* __restrict__ d2,
                             unsigned short* __restrict__ w1hi, unsigned short* __restrict__ w1lo,
                             unsigned short* __restrict__ wchi, unsigned short* __restrict__ wclo)
{
    int idx = blockIdx.x * 256 + threadIdx.x;
    if (idx < 96 * WINDOW) {
        int row = idx >> 7, k = idx & 127;
        float v;
        if (row < 64) v = (row & 1) ? b1i[(row >> 1) * WINDOW + k] : b1r[(row >> 1) * WINDOW + k];
        else          v = d1[(row - 64) * WINDOW + k];
        unsigned h = bf16r(v);
        w1hi[idx] = (unsigned short)h;
        w1lo[idx] = (unsigned short)bf16r(v - bf2f(h));
    } else if (idx < 96 * WINDOW + O2 * 96) {
        int j = idx - 96 * WINDOW;
        int row = j / 96, k = j - row * 96;
        float v;
        if (k < 64) v = (k & 1) ? -c2i[row * H + (k >> 1)] : c2r[row * H + (k >> 1)];
        else        v = d2[row * H + (k - 64)];
        unsigned h = bf16r(v);
        wchi[j] = (unsigned short)h;
        wclo[j] = (unsigned short)bf16r(v - bf2f(h));
    }
}

// ---------------------------------------------------------------------------
// Fused kernel: x -> out. 512 blocks x 512 threads, 2 blocks/CU.
// ---------------------------------------------------------------------------
__global__ __launch_bounds__(512, 4)
void lru_fused(const float* __restrict__ x,
               const float* __restrict__ nu1, const float* __restrict__ th1,
               const float* __restrict__ c1r, const float* __restrict__ c1i,
               const float* __restrict__ mlp_w, const float* __restrict__ mlp_b,
               const float* __restrict__ b2r, const float* __restrict__ b2i,
               const float* __restrict__ nu2, const float* __restrict__ th2,
               const unsigned short* __restrict__ w1hi, const unsigned short* __restrict__ w1lo,
               const unsigned short* __restrict__ wchi, const unsigned short* __restrict__ wclo,
               float* __restrict__ out)
{
    __shared__ __align__(16) char smem[S_LDS];
    const int tid = threadIdx.x;
    const int t0 = blockIdx.x * FO_BLK;
    const int frame0 = t0 - 64;              // global frame of staged idx 0
    const int w = tid >> 6, l = tid & 63, l15 = l & 15, lq = l >> 4;

    // ================= phase 0: small weights -> LDS ==========================
    // C1cat [32][64]: k even -> c1r, k odd -> -c1i
    {
        unsigned short* hi = (unsigned short*)(smem + OFF_C1HI);
        unsigned short* lo = (unsigned short*)(smem + OFF_C1LO);
        #pragma unroll
        for (int p = 0; p < 4; ++p) {
            int idx = tid + 512 * p;
            int row = idx >> 6, k = idx & 63;
            float v = (k & 1) ? -c1i[row * H + (k >> 1)] : c1r[row * H + (k >> 1)];
            unsigned h = bf16r(v);
            hi[row * 68 + k] = (unsigned short)h;      // 68 shorts = 136B pitch
            lo[row * 68 + k] = (unsigned short)bf16r(v - bf2f(h));
        }
    }
    // mlpw^T [32][32]
    {
        unsigned short* hi = (unsigned short*)(smem + OFF_MWHI);
        unsigned short* lo = (unsigned short*)(smem + OFF_MWLO);
        #pragma unroll
        for (int p = 0; p < 2; ++p) {
            int idx = tid + 512 * p;
            int row = idx >> 5, k = idx & 31;
            float v = mlp_w[k * H + row];
            unsigned h = bf16r(v);
            hi[row * 36 + k] = (unsigned short)h;      // 36 shorts = 72B pitch
            lo[row * 36 + k] = (unsigned short)bf16r(v - bf2f(h));
        }
    }
    // b2cat [64][32]: rows interleaved (2c=b2r[c], 2c+1=b2i[c])
    {
        unsigned short* hi = (unsigned short*)(smem + OFF_B2HI);
        unsigned short* lo = (unsigned short*)(smem + OFF_B2LO);
        #pragma unroll
        for (int p = 0; p < 4; ++p) {
            int idx = tid + 512 * p;
            int row = idx >> 5, k = idx & 31;
            float v = (row & 1) ? b2i[(row >> 1) * H + k] : b2r[(row >> 1) * H + k];
            unsigned h = bf16r(v);
            hi[row * 36 + k] = (unsigned short)h;
            lo[row * 36 + k] = (unsigned short)bf16r(v - bf2f(h));
        }
    }
    if (tid < H) ((float*)(smem + OFF_BIAS))[tid] = mlp_b[tid];
    __syncthreads();

    // ================= GEMM1: U1 (96 x 192) = W1 @ X ==========================
    // 12 N-tiles: wave w owns {w, w+8} (guard nt<12). A streamed from L2.
    {
        f32x4 acc1[2][6];
        #pragma unroll
        for (int ni = 0; ni < 2; ++ni)
            #pragma unroll
            for (int m = 0; m < 6; ++m) acc1[ni][m] = f32x4{0.f, 0.f, 0.f, 0.f};

        #pragma unroll 1
        for (int ks = 0; ks < 4; ++ks) {
            bf16x8 ah[6], al[6];
            #pragma unroll
            for (int m = 0; m < 6; ++m) {
                int ro = (m * 16 + l15) * WINDOW + ks * 32 + lq * 8;
                ah[m] = *(const bf16x8*)(w1hi + ro);
                al[m] = *(const bf16x8*)(w1lo + ro);
            }
            #pragma unroll
            for (int ni = 0; ni < 2; ++ni) {
                int nt = w + ni * 8;
                if (nt < 12) {
                    int gf = frame0 + nt * 16 + l15;
                    float4 xa{}, xb{};
                    if (gf >= 0) {
                        const float4* xp = (const float4*)(x + (size_t)gf * WINDOW + ks * 32 + lq * 8);
                        xa = xp[0]; xb = xp[1];
                    }
                    bf16x8 b = cvt8(xa, xb);
                    #pragma unroll
                    for (int m = 0; m < 6; ++m) {
                        acc1[ni][m] = __builtin_amdgcn_mfma_f32_16x16x32_bf16(ah[m], b, acc1[ni][m], 0, 0, 0);
                        acc1[ni][m] = __builtin_amdgcn_mfma_f32_16x16x32_bf16(al[m], b, acc1[ni][m], 0, 0, 0);
                    }
                }
            }
        }
        // epilogue: rows 0..63 -> u1 (R1), rows 64..95 -> d1x (R2, mid frames)
        #pragma unroll
        for (int ni = 0; ni < 2; ++ni) {
            int nt = w + ni * 8;
            if (nt < 12) {
                int fs = nt * 16 + l15;
                #pragma unroll
                for (int m = 0; m < 4; ++m) {
                    u16x4 pk;
                    #pragma unroll
                    for (int j = 0; j < 4; ++j) pk[j] = (unsigned short)bf16r(acc1[ni][m][j]);
                    *(u16x4*)(smem + OFF_R1 + fs * 132 + (m * 16 + lq * 4) * 2) = pk;
                }
                if (fs >= 32) {
                    int fm = fs - 32;
                    #pragma unroll
                    for (int m = 4; m < 6; ++m) {
                        u16x4 pk;
                        #pragma unroll
                        for (int j = 0; j < 4; ++j) pk[j] = (unsigned short)bf16r(acc1[ni][m][j]);
                        *(u16x4*)(smem + OFF_R2 + fm * 72 + ((m - 4) * 16 + lq * 4) * 2) = pk;
                    }
                }
            }
        }
    }
    __syncthreads();

    // ================= conv1: u1 -> h1 (160 mid frames) =======================
    {
        int c = tid & 31, g = tid >> 5;          // 16 groups x 10 frames
        float enu = expf(nu1[c]);
        float mag = expf(-enu);
        float ang = expf(th1[c]);
        float lr = mag * cosf(ang), li = mag * sinf(ang);
        float gam = sqrtf(fmaxf(1.0f - mag * mag, 0.0f));
        int fmb = g * 10;
        float hre = 0.f, him = 0.f;
        float pr = gam, pi = 0.f;                // gamma * lam^j, built on the fly
        #pragma unroll 4
        for (int j = 0; j < WU; ++j) {
            unsigned uw = *(const unsigned*)(smem + OFF_R1 + (fmb + 32 - j) * 132 + c * 4);
            float ur = bf2f(uw & 0xFFFFu), ui = bf2f(uw >> 16);
            hre = fmaf(pr, ur, hre); hre = fmaf(-pi, ui, hre);
            him = fmaf(pr, ui, him); him = fmaf(pi, ur, him);
            float npr = pr * lr - pi * li, npi = pr * li + pi * lr;
            pr = npr; pi = npi;
        }
        *(unsigned*)(smem + OFF_R3 + fmb * 136 + c * 4) = (bf16r(him) << 16) | bf16r(hre);
        #pragma unroll
        for (int s = 1; s < 10; ++s) {
            unsigned uw = *(const unsigned*)(smem + OFF_R1 + (fmb + 32 + s) * 132 + c * 4);
            float ur = bf2f(uw & 0xFFFFu), ui = bf2f(uw >> 16);
            float nre = lr * hre - li * him + gam * ur;
            float nim = lr * him + li * hre + gam * ui;
            hre = nre; him = nim;
            *(unsigned*)(smem + OFF_R3 + (fmb + s) * 136 + c * 4) = (bf16r(him) << 16) | bf16r(hre);
        }
    }
    __syncthreads();

    // ================= GEMM2: y1 = C1cat @ h1 + d1x ; selu -> y1s (R1) ========
    #pragma unroll 1
    for (int ci = w; ci < 20; ci += 8) {
        int n = ci >> 1, m = ci & 1;
        int fcol = n * 16 + l15;
        u16x4 dk = *(const u16x4*)(smem + OFF_R2 + fcol * 72 + (m * 16 + lq * 4) * 2);
        f32x4 c;
        #pragma unroll
        for (int j = 0; j < 4; ++j) c[j] = bf2f(dk[j]);
        #pragma unroll
        for (int ks = 0; ks < 2; ++ks) {
            int ao = (m * 16 + l15) * 136 + ks * 64 + lq * 16;
            bf16x8 ah = *(const bf16x8*)(smem + OFF_C1HI + ao);
            bf16x8 al = *(const bf16x8*)(smem + OFF_C1LO + ao);
            bf16x8 bb = *(const bf16x8*)(smem + OFF_R3 + fcol * 136 + ks * 64 + lq * 16);
            c = __builtin_amdgcn_mfma_f32_16x16x32_bf16(ah, bb, c, 0, 0, 0);
            c = __builtin_amdgcn_mfma_f32_16x16x32_bf16(al, bb, c, 0, 0, 0);
        }
        u16x4 pk;
        #pragma unroll
        for (int j = 0; j < 4; ++j) pk[j] = (unsigned short)bf16r(selu_f(c[j]));
        *(u16x4*)(smem + OFF_R1 + fcol * 72 + (m * 16 + lq * 4) * 2) = pk;
    }
    __syncthreads();

    // ================= MLP: y2 = mlpw^T @ y1s + bias ; selu -> y2l (R2) =======
    #pragma unroll 1
    for (int ci = w; ci < 20; ci += 8) {
        int n = ci >> 1, m = ci & 1;
        int fcol = n * 16 + l15;
        f32x4 c = *(const f32x4*)(smem + OFF_BIAS + (m * 16 + lq * 4) * 4);
        {
            int ao = (m * 16 + l15) * 72 + lq * 16;
            bf16x8 ah = *(const bf16x8*)(smem + OFF_MWHI + ao);
            bf16x8 al = *(const bf16x8*)(smem + OFF_MWLO + ao);
            bf16x8 bb = *(const bf16x8*)(smem + OFF_R1 + fcol * 72 + lq * 16);
            c = __builtin_amdgcn_mfma_f32_16x16x32_bf16(ah, bb, c, 0, 0, 0);
            c = __builtin_amdgcn_mfma_f32_16x16x32_bf16(al, bb, c, 0, 0, 0);
        }
        u16x4 pk;
        #pragma unroll
        for (int j = 0; j < 4; ++j) pk[j] = (unsigned short)bf16r(selu_f(c[j]));
        *(u16x4*)(smem + OFF_R2 + fcol * 72 + (m * 16 + lq * 4) * 2) = pk;
    }
    __syncthreads();

    // ================= GEMM3: u2 = b2cat @ y2l -> u2s (R3) ====================
    #pragma unroll 1
    for (int ci = w; ci < 40; ci += 8) {
        int n = ci >> 2, m = ci & 3;
        int fcol = n * 16 + l15;
        f32x4 c = f32x4{0.f, 0.f, 0.f, 0.f};
        {
            int ao = (m * 16 + l15) * 72 + lq * 16;
            bf16x8 ah = *(const bf16x8*)(smem + OFF_B2HI + ao);
            bf16x8 al = *(const bf16x8*)(smem + OFF_B2LO + ao);
            bf16x8 bb = *(const bf16x8*)(smem + OFF_R2 + fcol * 72 + lq * 16);
            c = __builtin_amdgcn_mfma_f32_16x16x32_bf16(ah, bb, c, 0, 0, 0);
            c = __builtin_amdgcn_mfma_f32_16x16x32_bf16(al, bb, c, 0, 0, 0);
        }
        if (t0 - 32 + fcol < 0) c = f32x4{0.f, 0.f, 0.f, 0.f};   // pre-history is zero
        u16x4 pk;
        #pragma unroll
        for (int j = 0; j < 4; ++j) pk[j] = (unsigned short)bf16r(c[j]);
        *(u16x4*)(smem + OFF_R3 + fcol * 132 + (m * 16 + lq * 4) * 2) = pk;
    }
    __syncthreads();

    // ================= conv2: u2s -> h2 (R1, 128 out frames) ==================
    {
        int c = tid & 31, g = tid >> 5;          // 16 groups x 8 frames
        float enu = expf(nu2[c]);
        float mag = expf(-enu);
        float ang = expf(th2[c]);
        float lr = mag * cosf(ang), li = mag * sinf(ang);
        float gam = sqrtf(fmaxf(1.0f - mag * mag, 0.0f));
        int fob = g * 8;
        float hre = 0.f, him = 0.f;
        float pr = gam, pi = 0.f;
        #pragma unroll 4
        for (int j = 0; j < WU; ++j) {
            unsigned uw = *(const unsigned*)(smem + OFF_R3 + (fob + 32 - j) * 132 + c * 4);
            float ur = bf2f(uw & 0xFFFFu), ui = bf2f(uw >> 16);
            hre = fmaf(pr, ur, hre); hre = fmaf(-pi, ui, hre);
            him = fmaf(pr, ui, him); him = fmaf(pi, ur, him);
            float npr = pr * lr - pi * li, npi = pr * li + pi * lr;
            pr = npr; pi = npi;
        }
        *(unsigned*)(smem + OFF_R1 + fob * 136 + c * 4) = (bf16r(him) << 16) | bf16r(hre);
        #pragma unroll
        for (int s = 1; s < 8; ++s) {
            unsigned uw = *(const unsigned*)(smem + OFF_R3 + (fob + 32 + s) * 132 + c * 4);
            float ur = bf2f(uw & 0xFFFFu), ui = bf2f(uw >> 16);
            float nre = lr * hre - li * him + gam * ur;
            float nim = lr * him + li * hre + gam * ui;
            hre = nre; him = nim;
            *(unsigned*)(smem + OFF_R1 + (fob + s) * 136 + c * 4) = (bf16r(him) << 16) | bf16r(hre);
        }
    }
    __syncthreads();

    // ================= GEMM4: out = wcat @ [h2 ; y2] ==========================
    // wave w owns M-tiles {2w, 2w+1}; 8 N-tiles of 16 frames. A streamed from L2.
    {
        f32x4 acc[2][8];
        #pragma unroll
        for (int mi = 0; mi < 2; ++mi)
            #pragma unroll
            for (int n = 0; n < 8; ++n) acc[mi][n] = f32x4{0.f, 0.f, 0.f, 0.f};

        #pragma unroll 1
        for (int ks = 0; ks < 3; ++ks) {
            bf16x8 ah[2], al[2];
            #pragma unroll
            for (int mi = 0; mi < 2; ++mi) {
                int row = (2 * w + mi) * 16 + l15;
                ah[mi] = *(const bf16x8*)(wchi + row * 96 + ks * 32 + lq * 8);
                al[mi] = *(const bf16x8*)(wclo + row * 96 + ks * 32 + lq * 8);
            }
            #pragma unroll
            for (int n = 0; n < 8; ++n) {
                int fcol = n * 16 + l15;
                bf16x8 bb;
                if (ks < 2) bb = *(const bf16x8*)(smem + OFF_R1 + fcol * 136 + ks * 64 + lq * 16);
                else        bb = *(const bf16x8*)(smem + OFF_R2 + (fcol + 32) * 72 + lq * 16);
                #pragma unroll
                for (int mi = 0; mi < 2; ++mi) {
                    acc[mi][n] = __builtin_amdgcn_mfma_f32_16x16x32_bf16(ah[mi], bb, acc[mi][n], 0, 0, 0);
                    acc[mi][n] = __builtin_amdgcn_mfma_f32_16x16x32_bf16(al[mi], bb, acc[mi][n], 0, 0, 0);
                }
            }
        }
        #pragma unroll
        for (int mi = 0; mi < 2; ++mi) {
            int row0 = (2 * w + mi) * 16 + lq * 4;
            #pragma unroll
            for (int n = 0; n < 8; ++n) {
                int t = t0 + n * 16 + l15;
                #pragma unroll
                for (int j = 0; j < 4; ++j)
                    __builtin_nontemporal_store(acc[mi][n][j], &out[(size_t)(row0 + j) * LFRAMES + t]);
            }
        }
    }
}

extern "C" void kernel_launch(void* const* d_in, const int* in_sizes, int n_in,
                              void* d_out, int out_size, void* d_ws, size_t ws_size,
                              hipStream_t stream)
{
    const float* x     = (const float*)d_in[0];
    const float* b1r   = (const float*)d_in[1];
    const float* b1i   = (const float*)d_in[2];
    const float* nu1   = (const float*)d_in[3];
    const float* th1   = (const float*)d_in[4];
    const float* c1r   = (const float*)d_in[5];
    const float* c1i   = (const float*)d_in[6];
    const float* d1    = (const float*)d_in[7];
    const float* mlp_w = (const float*)d_in[8];
    const float* mlp_b = (const float*)d_in[9];
    const float* b2r   = (const float*)d_in[10];
    const float* b2i   = (const float*)d_in[11];
    const float* nu2   = (const float*)d_in[12];
    const float* th2   = (const float*)d_in[13];
    const float* c2r   = (const float*)d_in[14];
    const float* c2i   = (const float*)d_in[15];
    const float* d2    = (const float*)d_in[16];
    float* out = (float*)d_out;

    // ws layout: w1hi 24576 | w1lo 24576 | wchi 49152 | wclo 49152
    unsigned short* w1hi = (unsigned short*)d_ws;
    unsigned short* w1lo = (unsigned short*)((char*)d_ws + 24576);
    unsigned short* wchi = (unsigned short*)((char*)d_ws + 49152);
    unsigned short* wclo = (unsigned short*)((char*)d_ws + 98304);

    prep_weights<<<dim3((96 * WINDOW + O2 * 96 + 255) / 256), dim3(256), 0, stream>>>(
        b1r, b1i, d1, c2r, c2i, d2, w1hi, w1lo, wchi, wclo);

    lru_fused<<<dim3(LFRAMES / FO_BLK), dim3(512), 0, stream>>>(
        x, nu1, th1, c1r, c1i, mlp_w, mlp_b, b2r, b2i, nu2, th2,
        w1hi, w1lo, wchi, wclo, out);
}